// Round 5
// baseline (5002.543 us; speedup 1.0000x reference)
//
#include <hip/hip_runtime.h>
#include <hip/hip_fp16.h>
#include <cstdint>
#include <cstddef>

#define T_STEPS 512
#define HID 40
#define GATES 120

// Single-wave-block "barrier": lanes lockstep; only LDS completion ordering needed.
// Never touches vmcnt, so global prefetch loads / output stores stay in flight.
__device__ __forceinline__ void wavesync() { asm volatile("s_waitcnt lgkmcnt(0)" ::: "memory"); }
__device__ __forceinline__ float bperm(int srclane, float v) {
    return __int_as_float(__builtin_amdgcn_ds_bpermute(srclane << 2, __float_as_int(v)));
}
__device__ __forceinline__ float sigm(float x) { return 1.f / (1.f + __expf(-x)); }

// Fold MLP second linear into the next GRU's input weights:
// wih_eff[g][j] = sum_k wih[g][k] * w2[k][j];  bih_eff[g] = bih[g] + sum_k wih[g][k]*b2[k]
__global__ __launch_bounds__(64) void fold_w2(
    const float* __restrict__ g_wih,   // [4][120][40]
    const float* __restrict__ g_bih,   // [4][120]
    const float* __restrict__ mlp_w2,  // [3][40][40]
    const float* __restrict__ mlp_b2,  // [3][40]
    float* __restrict__ wih_eff,       // [3][120][40]
    float* __restrict__ bih_eff)       // [3][120]
{
    const int li = blockIdx.y;   // 0..2  (maps to g index li+1)
    const int g  = blockIdx.x;   // 0..119
    const int j  = threadIdx.x;  // 0..63
    const float* wrow = g_wih + ((size_t)(li + 1) * GATES + g) * HID;
    if (j < HID) {
        float acc = 0.f;
        #pragma unroll 8
        for (int k = 0; k < HID; ++k)
            acc += wrow[k] * mlp_w2[((size_t)li * HID + k) * HID + j];
        wih_eff[((size_t)li * GATES + g) * HID + j] = acc;
    }
    if (j == HID) {
        float acc = g_bih[(size_t)(li + 1) * GATES + g];
        #pragma unroll 8
        for (int k = 0; k < HID; ++k)
            acc += wrow[k] * mlp_b2[(size_t)li * HID + k];
        bih_eff[(size_t)li * GATES + g] = acc;
    }
}

// Time-parallel precompute: xp[i][g] = bih[g] + wih[g] . v_i   (f16 output),
// where v_i = leaky(w1 . x_i + b1) if FUSE else x_i.  One thread per (e,t) row.
// Weight indices are uniform -> compiler emits scalar s_loads (SMEM), VALU does
// only the per-row FMAs.
template<int DIN, bool FUSE>
__global__ __launch_bounds__(256) void precomp(
    const float* __restrict__ in,    // [nrows, DIN]
    __half* __restrict__ xp,         // [nrows, 120]
    const float* __restrict__ wih,   // [120, FUSE?40:DIN] (w2-folded if FUSE)
    const float* __restrict__ bih,   // [120]
    const float* __restrict__ w1,    // [40,40] or null
    const float* __restrict__ b1,    // [40] or null
    int nrows)
{
    const int i = blockIdx.x * 256 + threadIdx.x;
    if (i >= nrows) return;

    float x[DIN];
    {
        const float4* xr = reinterpret_cast<const float4*>(in + (size_t)i * DIN);
        #pragma unroll
        for (int k = 0; k < DIN / 4; ++k) reinterpret_cast<float4*>(x)[k] = xr[k];
    }

    constexpr int VD = FUSE ? HID : DIN;
    float v[VD];
    if constexpr (FUSE) {
        #pragma unroll 4
        for (int j = 0; j < HID; ++j) {
            float acc = b1[j];
            #pragma unroll
            for (int k = 0; k < DIN; ++k) acc += w1[j * DIN + k] * x[k];
            v[j] = acc > 0.f ? acc : 0.01f * acc;
        }
    } else {
        #pragma unroll
        for (int k = 0; k < DIN; ++k) v[k] = x[k];
    }

    __half* xrow = xp + (size_t)i * GATES;
    #pragma unroll
    for (int c = 0; c < 5; ++c) {           // 5 chunks of 24 gates
        alignas(16) __half hb[24];
        #pragma unroll 6
        for (int g = 0; g < 24; ++g) {
            const int gg = c * 24 + g;
            float acc = bih[gg];
            #pragma unroll
            for (int k = 0; k < VD; ++k) acc += wih[gg * VD + k] * v[k];
            hb[g] = __float2half(acc);
        }
        float4* dst = reinterpret_cast<float4*>(xrow + c * 24);
        const float4* src = reinterpret_cast<const float4*>(hb);
        dst[0] = src[0]; dst[1] = src[1]; dst[2] = src[2];
    }
}

// Recurrence-only kernel: one wave per element, persistent over T steps.
// Per step: gates = xp_t (precomputed, f16, global-prefetched 2 deep) + whh.h.
// Gate ownership: lane l<40: gA = r_l, gB = n_l (80+l).
//                 lane 40..63: gA = z_{l-40}; lanes 40..55: gB = z_{l-16}.
// r/n lane-local; z via one ds_bpermute pair. No barriers, lgkmcnt-only syncs.
template<bool WRITE_ALL>
__global__ __launch_bounds__(64) void gru_rec(
    const __half* __restrict__ xp,   // [CB, T, 120]
    float* __restrict__ out,         // [CB, T, 40]
    const float* __restrict__ whh,   // [120, 40]
    const float* __restrict__ bhh)   // [120]
{
    __shared__ float s_h[64];

    const int lane = threadIdx.x;
    const int e    = blockIdx.x;

    const int gA = lane;
    const int gB = (lane < 40) ? (80 + lane) : ((lane < 56) ? (24 + lane) : lane);

    float whA[HID], whB[HID];
    {
        const float4* hv = reinterpret_cast<const float4*>(whh);
        #pragma unroll
        for (int k = 0; k < HID / 4; ++k) {
            reinterpret_cast<float4*>(whA)[k] = hv[gA * (HID / 4) + k];
            reinterpret_cast<float4*>(whB)[k] = hv[gB * (HID / 4) + k];
        }
    }
    const float bhA = bhh[gA], bhB = bhh[gB];

    const __half* xpb  = xp  + (size_t)e * T_STEPS * GATES;
    float*        outb = out + (size_t)e * T_STEPS * HID;

    float hreg = 0.f;
    s_h[lane] = 0.f;

    // prefetch xp for t=0,1 (stays in flight across wavesync: vmcnt untouched)
    __half a0 = xpb[gA],         b0 = xpb[gB];
    __half a1 = xpb[GATES + gA], b1 = xpb[GATES + gB];
    wavesync();

    for (int t = 0; t < T_STEPS; ++t) {
        // issue prefetch for t+2
        __half a2 = a0, b2 = b0;
        if (t + 2 < T_STEPS) {
            a2 = xpb[(size_t)(t + 2) * GATES + gA];
            b2 = xpb[(size_t)(t + 2) * GATES + gB];
        }

        // h-dot: weights in VGPRs, h uniform-broadcast from LDS.
        float4 hA = {0,0,0,0}, hB = {0,0,0,0};
        #pragma unroll
        for (int k = 0; k < HID / 4; ++k) {
            const float4 v = reinterpret_cast<const float4*>(s_h)[k];
            hA.x += whA[4*k+0]*v.x; hA.y += whA[4*k+1]*v.y;
            hA.z += whA[4*k+2]*v.z; hA.w += whA[4*k+3]*v.w;
            hB.x += whB[4*k+0]*v.x; hB.y += whB[4*k+1]*v.y;
            hB.z += whB[4*k+2]*v.z; hB.w += whB[4*k+3]*v.w;
        }
        const float shA = bhA + ((hA.x + hA.z) + (hA.y + hA.w));
        const float shB = bhB + ((hB.x + hB.z) + (hB.y + hB.w));
        const float xA  = __half2float(a0);
        const float xB  = __half2float(b0);
        const float sumA = xA + shA;
        const float sumB = xB + shB;
        // z_l: lane 40+l (sumA) for l<24, lane 16+l (sumB) for l>=24. All lanes execute.
        const float zA = bperm(40 + lane, sumA);
        const float zB = bperm(16 + lane, sumB);

        if (lane < HID) {
            const float r   = sigm(sumA);
            const float z   = sigm((lane < 24) ? zA : zB);
            const float pre = xB + r * shB;           // x_n + r*h_n (biases included)
            const float ex  = __expf(-2.f * pre);
            const float n   = (1.f - ex) / (1.f + ex);
            hreg = (1.f - z) * n + z * hreg;
            s_h[lane] = hreg;
            if constexpr (WRITE_ALL) {
                outb[(size_t)t * HID + lane] = hreg;
            } else {
                if (t == T_STEPS - 1) outb[(size_t)t * HID + lane] = hreg;
            }
        }
        a0 = a1; b0 = b1; a1 = a2; b1 = b2;
        wavesync();   // s_h staged for next step
    }
}

// lay8: a = leaky(h @ w1^T + b1); t = a . w_last + b_last; out = sigmoid(t)
// Reads h_last strided out of the activation buffer at [e][T-1][*].
__global__ __launch_bounds__(256) void final_head(
    const float* __restrict__ hbase,  // buf + (T-1)*HID
    float* __restrict__ outp,         // [CB]
    const float* __restrict__ w1, const float* __restrict__ b1,
    const float* __restrict__ wl, const float* __restrict__ bl, int n)
{
    __shared__ float s_w1[HID][HID + 1];
    __shared__ float s_b1[HID];
    __shared__ float s_wl[HID];
    for (int i = threadIdx.x; i < HID * HID; i += 256) s_w1[i / HID][i % HID] = w1[i];
    if (threadIdx.x < HID) { s_b1[threadIdx.x] = b1[threadIdx.x]; s_wl[threadIdx.x] = wl[threadIdx.x]; }
    __syncthreads();
    const int e = blockIdx.x * 256 + threadIdx.x;
    if (e >= n) return;
    float h[HID];
    const float4* hv = reinterpret_cast<const float4*>(hbase + (size_t)e * T_STEPS * HID);
    #pragma unroll
    for (int k = 0; k < HID / 4; ++k) reinterpret_cast<float4*>(h)[k] = hv[k];
    float acc = bl[0];
    #pragma unroll
    for (int u = 0; u < HID; ++u) {
        float a = s_b1[u];
        #pragma unroll
        for (int d = 0; d < HID; ++d) a += s_w1[u][d] * h[d];
        a = a > 0.f ? a : 0.01f * a;
        acc += a * s_wl[u];
    }
    outp[e] = 1.f / (1.f + __expf(-acc));
}

extern "C" void kernel_launch(void* const* d_in, const int* in_sizes, int n_in,
                              void* d_out, int out_size, void* d_ws, size_t ws_size,
                              hipStream_t stream)
{
    const float* x      = (const float*)d_in[0];
    const float* g0_wih = (const float*)d_in[1];
    const float* g0_whh = (const float*)d_in[2];
    const float* g0_bih = (const float*)d_in[3];
    const float* g0_bhh = (const float*)d_in[4];
    const float* g_wih  = (const float*)d_in[5];   // [4,120,40]
    const float* g_whh  = (const float*)d_in[6];   // [4,120,40]
    const float* g_bih  = (const float*)d_in[7];   // [4,120]
    const float* g_bhh  = (const float*)d_in[8];   // [4,120]
    const float* mlp_w1 = (const float*)d_in[9];   // [4,40,40]
    const float* mlp_b1 = (const float*)d_in[10];  // [4,40]
    const float* mlp_w2 = (const float*)d_in[11];  // [3,40,40]
    const float* mlp_b2 = (const float*)d_in[12];  // [3,40]
    const float* w_last = (const float*)d_in[13];  // [1,40]
    const float* b_last = (const float*)d_in[14];  // [1]

    const int B = in_sizes[0] / (T_STEPS * 20);
    float* out = (float*)d_out;

    // ws layout: [wih_eff 3*4800 f32][bih_eff 3*120 f32][hbuf CB*T*40 f32][xpbuf CB*T*120 f16]
    float* wih_eff = (float*)d_ws;
    float* bih_eff = wih_eff + 3 * GATES * HID;
    float* hbuf    = bih_eff + 3 * GATES;
    const size_t wbytes = (size_t)(3 * GATES * HID + 3 * GATES) * sizeof(float);
    const size_t ws_rem = ws_size - wbytes;

    fold_w2<<<dim3(GATES, 3), 64, 0, stream>>>(g_wih, g_bih, mlp_w2, mlp_b2,
                                               wih_eff, bih_eff);

    // bytes per chunk element: h (T*40*4) + xp (T*120*2)
    const size_t per_e = (size_t)T_STEPS * (HID * 4 + GATES * 2);
    int CB = B;
    while ((size_t)CB * per_e > ws_rem && CB > 64) CB >>= 1;
    __half* xpbuf = (__half*)(hbuf + (size_t)CB * T_STEPS * HID);

    for (int c = 0; c < B; c += CB) {
        const int   nrows = CB * T_STEPS;
        const dim3  pgrd(nrows / 256), pblk(256);
        const dim3  rgrd(CB), rblk(64);
        const float* xc = x + (size_t)c * T_STEPS * 20;

        // lay1 layer-0 (DIN=20)
        precomp<20, false><<<pgrd, pblk, 0, stream>>>(
            xc, xpbuf, g0_wih, g0_bih, nullptr, nullptr, nrows);
        gru_rec<true><<<rgrd, rblk, 0, stream>>>(xpbuf, hbuf, g0_whh, g0_bhh);
        // lay1 layer-1 (DIN=40, no MLP)
        precomp<40, false><<<pgrd, pblk, 0, stream>>>(
            hbuf, xpbuf, g_wih + 0 * 4800, g_bih + 0 * 120, nullptr, nullptr, nrows);
        gru_rec<true><<<rgrd, rblk, 0, stream>>>(xpbuf, hbuf, g_whh + 0 * 4800, g_bhh + 0 * 120);
        // lay2..7: (MLP_i folded) + GRU g[i+1]
        for (int li = 0; li < 3; ++li) {
            precomp<40, true><<<pgrd, pblk, 0, stream>>>(
                hbuf, xpbuf, wih_eff + li * 4800, bih_eff + li * 120,
                mlp_w1 + li * 1600, mlp_b1 + li * 40, nrows);
            if (li < 2)
                gru_rec<true><<<rgrd, rblk, 0, stream>>>(
                    xpbuf, hbuf, g_whh + (li + 1) * 4800, g_bhh + (li + 1) * 120);
            else
                gru_rec<false><<<rgrd, rblk, 0, stream>>>(
                    xpbuf, hbuf, g_whh + (li + 1) * 4800, g_bhh + (li + 1) * 120);
        }
        // lay8 head on h[:, -1]
        final_head<<<dim3((CB + 255) / 256), dim3(256), 0, stream>>>(
            hbuf + (size_t)(T_STEPS - 1) * HID, out + c,
            mlp_w1 + 3 * 1600, mlp_b1 + 3 * 40, w_last, b_last, CB);
    }
}

// Round 6
// 3591.008 us; speedup vs baseline: 1.3931x; 1.3931x over previous
//
#include <hip/hip_runtime.h>
#include <hip/hip_fp16.h>
#include <cstdint>
#include <cstddef>

#define T_STEPS 512
#define HID 40
#define GATES 120

// Single-wave-block "barrier": lanes lockstep; only LDS completion ordering needed.
// Never touches vmcnt, so global prefetch loads / output stores stay in flight.
__device__ __forceinline__ void wavesync() { asm volatile("s_waitcnt lgkmcnt(0)" ::: "memory"); }
__device__ __forceinline__ float bperm(int srclane, float v) {
    return __int_as_float(__builtin_amdgcn_ds_bpermute(srclane << 2, __float_as_int(v)));
}
__device__ __forceinline__ float sigm(float x) { return 1.f / (1.f + __expf(-x)); }

// Fold MLP second linear into the next GRU's input weights:
// wih_eff[g][j] = sum_k wih[g][k] * w2[k][j];  bih_eff[g] = bih[g] + sum_k wih[g][k]*b2[k]
__global__ __launch_bounds__(64) void fold_w2(
    const float* __restrict__ g_wih,   // [4][120][40]
    const float* __restrict__ g_bih,   // [4][120]
    const float* __restrict__ mlp_w2,  // [3][40][40]
    const float* __restrict__ mlp_b2,  // [3][40]
    float* __restrict__ wih_eff,       // [3][120][40]
    float* __restrict__ bih_eff)       // [3][120]
{
    const int li = blockIdx.y;   // 0..2  (maps to g index li+1)
    const int g  = blockIdx.x;   // 0..119
    const int j  = threadIdx.x;  // 0..63
    const float* wrow = g_wih + ((size_t)(li + 1) * GATES + g) * HID;
    if (j < HID) {
        float acc = 0.f;
        #pragma unroll 8
        for (int k = 0; k < HID; ++k)
            acc += wrow[k] * mlp_w2[((size_t)li * HID + k) * HID + j];
        wih_eff[((size_t)li * GATES + g) * HID + j] = acc;
    }
    if (j == HID) {
        float acc = g_bih[(size_t)(li + 1) * GATES + g];
        #pragma unroll 8
        for (int k = 0; k < HID; ++k)
            acc += wrow[k] * mlp_b2[(size_t)li * HID + k];
        bih_eff[(size_t)li * GATES + g] = acc;
    }
}

// Time-parallel gate precompute: one thread per (e,t) row.
// xp[i][g] = bih[g] + wih[g] . v_i, f16 out; v_i = leaky(w1.x_i+b1) if FUSE else x_i.
// Weights staged in LDS, read as uniform-address b128 broadcasts (conflict-free).
// All register arrays use compile-time indices only (no alloca->LDS promotion).
// F32IN: in is fp32 [nrows,DIN]. Else: in is f16 xp-layout rows (stride 120, h at [0:40]).
// in/xp may alias (per-thread read-row-then-write-row): no __restrict__ on them.
template<bool F32IN, int DIN, bool FUSE>
__global__ __launch_bounds__(256) void precomp(
    const void* in_, __half* xp,
    const float* __restrict__ wih,   // [120, VD]
    const float* __restrict__ bih,   // [120]
    const float* __restrict__ w1,    // [40,40] or null
    const float* __restrict__ b1,    // [40] or null
    int nrows)
{
    constexpr int VD = FUSE ? HID : DIN;
    __shared__ float s_wih[GATES * VD];
    __shared__ float s_bih[GATES];
    __shared__ float s_w1[FUSE ? HID * HID : 1];
    __shared__ float s_b1[FUSE ? HID : 1];

    for (int idx = threadIdx.x; idx < GATES * VD; idx += 256) s_wih[idx] = wih[idx];
    if (threadIdx.x < GATES) s_bih[threadIdx.x] = bih[threadIdx.x];
    if constexpr (FUSE) {
        for (int idx = threadIdx.x; idx < HID * HID; idx += 256) s_w1[idx] = w1[idx];
        if (threadIdx.x < HID) s_b1[threadIdx.x] = b1[threadIdx.x];
    }
    __syncthreads();

    const int i = blockIdx.x * 256 + threadIdx.x;
    if (i >= nrows) return;

    float x[DIN];
    if constexpr (F32IN) {
        const float4* xr = reinterpret_cast<const float4*>((const float*)in_ + (size_t)i * DIN);
        #pragma unroll
        for (int q = 0; q < DIN / 4; ++q) reinterpret_cast<float4*>(x)[q] = xr[q];
    } else {
        alignas(16) __half hx[DIN];
        const uint4* hr = reinterpret_cast<const uint4*>((const __half*)in_ + (size_t)i * GATES);
        #pragma unroll
        for (int q = 0; q < DIN / 8; ++q) reinterpret_cast<uint4*>(hx)[q] = hr[q];
        #pragma unroll
        for (int k = 0; k < DIN; ++k) x[k] = __half2float(hx[k]);
    }

    float v[VD];
    if constexpr (FUSE) {
        // fully unrolled 40x40 MLP: v indices compile-time, weights LDS-broadcast
        #pragma unroll
        for (int j = 0; j < HID; ++j) {
            float a0 = 0.f, a1 = 0.f, a2 = 0.f, a3 = 0.f;
            #pragma unroll
            for (int q = 0; q < HID / 4; ++q) {
                const float4 w = *reinterpret_cast<const float4*>(&s_w1[j * HID + 4 * q]);
                a0 += w.x * x[4*q+0]; a1 += w.y * x[4*q+1];
                a2 += w.z * x[4*q+2]; a3 += w.w * x[4*q+3];
            }
            const float a = s_b1[j] + ((a0 + a2) + (a1 + a3));
            v[j] = a > 0.f ? a : 0.01f * a;
        }
    } else {
        #pragma unroll
        for (int k = 0; k < DIN; ++k) v[k] = x[k];
    }

    // gates in chunks of 8 (runtime c-loop keeps code size sane; all register
    // indices inside are compile-time)
    __half* orow = xp + (size_t)i * GATES;
    #pragma unroll 1
    for (int c = 0; c < GATES / 8; ++c) {
        float acc[8];
        #pragma unroll
        for (int g = 0; g < 8; ++g) {
            float a0 = 0.f, a1 = 0.f, a2 = 0.f, a3 = 0.f;
            const float* wr = &s_wih[(c * 8 + g) * VD];
            #pragma unroll
            for (int q = 0; q < VD / 4; ++q) {
                const float4 w = *reinterpret_cast<const float4*>(&wr[4 * q]);
                a0 += w.x * v[4*q+0]; a1 += w.y * v[4*q+1];
                a2 += w.z * v[4*q+2]; a3 += w.w * v[4*q+3];
            }
            acc[g] = s_bih[c * 8 + g] + ((a0 + a2) + (a1 + a3));
        }
        alignas(16) __half h8[8];
        #pragma unroll
        for (int g = 0; g < 8; ++g) h8[g] = __float2half(acc[g]);
        *reinterpret_cast<uint4*>(orow + c * 8) = *reinterpret_cast<const uint4*>(h8);
    }
}

// Recurrence-only kernel: one wave per element, persistent over T steps.
// gates = xp_t (f16, prefetched 2 deep) + whh.h; h_t (f16) is written back INTO
// xp row t bytes [0:80) — safe: all reads of row t happened at step t-2.
// Gate ownership: lane l<40: gA=r_l, gB=n_l(80+l); lane 40..63: gA=z_{l-40};
// lanes 40..55: gB=z_{l-16}. r/n lane-local; z via one ds_bpermute pair.
__global__ __launch_bounds__(64) void gru_rec(
    __half* xp,                      // [CB, T, 120], h written into [t][0:40]
    const float* __restrict__ whh,   // [120, 40]
    const float* __restrict__ bhh)   // [120]
{
    __shared__ float s_h[64];

    const int lane = threadIdx.x;
    const int e    = blockIdx.x;

    const int gA = lane;
    const int gB = (lane < 40) ? (80 + lane) : ((lane < 56) ? (24 + lane) : lane);

    float whA[HID], whB[HID];
    {
        const float4* hv = reinterpret_cast<const float4*>(whh);
        #pragma unroll
        for (int k = 0; k < HID / 4; ++k) {
            reinterpret_cast<float4*>(whA)[k] = hv[gA * (HID / 4) + k];
            reinterpret_cast<float4*>(whB)[k] = hv[gB * (HID / 4) + k];
        }
    }
    const float bhA = bhh[gA], bhB = bhh[gB];

    __half* xpb = xp + (size_t)e * T_STEPS * GATES;

    float hreg = 0.f;
    s_h[lane] = 0.f;

    // prefetch xp for t=0,1 (stays in flight across wavesync: vmcnt untouched)
    __half a0 = xpb[gA],         c0 = xpb[gB];
    __half a1 = xpb[GATES + gA], c1 = xpb[GATES + gB];
    wavesync();

    for (int t = 0; t < T_STEPS; ++t) {
        // issue prefetch for t+2
        __half a2 = a0, c2 = c0;
        if (t + 2 < T_STEPS) {
            a2 = xpb[(size_t)(t + 2) * GATES + gA];
            c2 = xpb[(size_t)(t + 2) * GATES + gB];
        }

        // h-dot: weights in VGPRs, h uniform-broadcast from LDS.
        float4 hA = {0,0,0,0}, hB = {0,0,0,0};
        #pragma unroll
        for (int k = 0; k < HID / 4; ++k) {
            const float4 v = reinterpret_cast<const float4*>(s_h)[k];
            hA.x += whA[4*k+0]*v.x; hA.y += whA[4*k+1]*v.y;
            hA.z += whA[4*k+2]*v.z; hA.w += whA[4*k+3]*v.w;
            hB.x += whB[4*k+0]*v.x; hB.y += whB[4*k+1]*v.y;
            hB.z += whB[4*k+2]*v.z; hB.w += whB[4*k+3]*v.w;
        }
        const float shA = bhA + ((hA.x + hA.z) + (hA.y + hA.w));
        const float shB = bhB + ((hB.x + hB.z) + (hB.y + hB.w));
        const float xA  = __half2float(a0);
        const float xB  = __half2float(c0);
        const float sumA = xA + shA;
        const float sumB = xB + shB;
        // z_l: lane 40+l (sumA) for l<24, lane 16+l (sumB) for l>=24. All lanes execute.
        const float zA = bperm(40 + lane, sumA);
        const float zB = bperm(16 + lane, sumB);

        if (lane < HID) {
            const float r   = sigm(sumA);
            const float z   = sigm((lane < 24) ? zA : zB);
            const float pre = xB + r * shB;           // x_n + r*h_n (biases included)
            const float ex  = __expf(-2.f * pre);
            const float n   = (1.f - ex) / (1.f + ex);
            hreg = (1.f - z) * n + z * hreg;
            s_h[lane] = hreg;
            xpb[(size_t)t * GATES + lane] = __float2half(hreg);  // h into row t
        }
        a0 = a1; c0 = c1; a1 = a2; c1 = c2;
        wavesync();   // s_h staged for next step
    }
}

// lay8: a = leaky(h @ w1^T + b1); t = a . w_last + b_last; out = sigmoid(t)
// Reads f16 h strided out of the xp buffer at [e][T-1][0:40].
__global__ __launch_bounds__(256) void final_head(
    const __half* __restrict__ hbase,  // xpbuf + (T-1)*GATES
    float* __restrict__ outp,          // [CB]
    const float* __restrict__ w1, const float* __restrict__ b1,
    const float* __restrict__ wl, const float* __restrict__ bl, int n)
{
    __shared__ float s_w1[HID][HID + 1];
    __shared__ float s_b1[HID];
    __shared__ float s_wl[HID];
    for (int i = threadIdx.x; i < HID * HID; i += 256) s_w1[i / HID][i % HID] = w1[i];
    if (threadIdx.x < HID) { s_b1[threadIdx.x] = b1[threadIdx.x]; s_wl[threadIdx.x] = wl[threadIdx.x]; }
    __syncthreads();
    const int e = blockIdx.x * 256 + threadIdx.x;
    if (e >= n) return;

    alignas(16) __half hx[HID];
    const uint4* hr = reinterpret_cast<const uint4*>(hbase + (size_t)e * T_STEPS * GATES);
    #pragma unroll
    for (int q = 0; q < HID / 8; ++q) reinterpret_cast<uint4*>(hx)[q] = hr[q];
    float h[HID];
    #pragma unroll
    for (int k = 0; k < HID; ++k) h[k] = __half2float(hx[k]);

    float acc = bl[0];
    #pragma unroll
    for (int u = 0; u < HID; ++u) {
        float a = s_b1[u];
        #pragma unroll
        for (int d = 0; d < HID; ++d) a += s_w1[u][d] * h[d];
        a = a > 0.f ? a : 0.01f * a;
        acc += a * s_wl[u];
    }
    outp[e] = 1.f / (1.f + __expf(-acc));
}

extern "C" void kernel_launch(void* const* d_in, const int* in_sizes, int n_in,
                              void* d_out, int out_size, void* d_ws, size_t ws_size,
                              hipStream_t stream)
{
    const float* x      = (const float*)d_in[0];
    const float* g0_wih = (const float*)d_in[1];
    const float* g0_whh = (const float*)d_in[2];
    const float* g0_bih = (const float*)d_in[3];
    const float* g0_bhh = (const float*)d_in[4];
    const float* g_wih  = (const float*)d_in[5];   // [4,120,40]
    const float* g_whh  = (const float*)d_in[6];   // [4,120,40]
    const float* g_bih  = (const float*)d_in[7];   // [4,120]
    const float* g_bhh  = (const float*)d_in[8];   // [4,120]
    const float* mlp_w1 = (const float*)d_in[9];   // [4,40,40]
    const float* mlp_b1 = (const float*)d_in[10];  // [4,40]
    const float* mlp_w2 = (const float*)d_in[11];  // [3,40,40]
    const float* mlp_b2 = (const float*)d_in[12];  // [3,40]
    const float* w_last = (const float*)d_in[13];  // [1,40]
    const float* b_last = (const float*)d_in[14];  // [1]

    const int B = in_sizes[0] / (T_STEPS * 20);
    float* out = (float*)d_out;

    // ws layout: [wih_eff 3*4800 f32][bih_eff 3*120 f32][xpbuf CB*T*120 f16]
    float* wih_eff = (float*)d_ws;
    float* bih_eff = wih_eff + 3 * GATES * HID;
    const size_t wbytes = (size_t)(3 * GATES * HID + 3 * GATES) * sizeof(float);
    __half* xpbuf = (__half*)((char*)d_ws + wbytes);
    const size_t ws_rem = ws_size - wbytes;

    fold_w2<<<dim3(GATES, 3), 64, 0, stream>>>(g_wih, g_bih, mlp_w2, mlp_b2,
                                               wih_eff, bih_eff);

    const size_t per_e = (size_t)T_STEPS * GATES * sizeof(__half);  // 240B/row
    int CB = B;
    while ((size_t)CB * per_e > ws_rem && CB > 64) CB >>= 1;

    for (int c = 0; c < B; c += CB) {
        const int  nrows = CB * T_STEPS;
        const dim3 pgrd((nrows + 255) / 256), pblk(256);
        const dim3 rgrd(CB), rblk(64);
        const float* xc = x + (size_t)c * T_STEPS * 20;

        // lay1 layer-0 (fp32 input, DIN=20)
        precomp<true, 20, false><<<pgrd, pblk, 0, stream>>>(
            xc, xpbuf, g0_wih, g0_bih, nullptr, nullptr, nrows);
        gru_rec<<<rgrd, rblk, 0, stream>>>(xpbuf, g0_whh, g0_bhh);
        // lay1 layer-1 (h f16 input, no MLP)
        precomp<false, 40, false><<<pgrd, pblk, 0, stream>>>(
            xpbuf, xpbuf, g_wih + 0 * 4800, g_bih + 0 * 120, nullptr, nullptr, nrows);
        gru_rec<<<rgrd, rblk, 0, stream>>>(xpbuf, g_whh + 0 * 4800, g_bhh + 0 * 120);
        // lay2..7: (MLP_i, w2 folded) + GRU g[i+1]
        for (int li = 0; li < 3; ++li) {
            precomp<false, 40, true><<<pgrd, pblk, 0, stream>>>(
                xpbuf, xpbuf, wih_eff + li * 4800, bih_eff + li * 120,
                mlp_w1 + li * 1600, mlp_b1 + li * 40, nrows);
            gru_rec<<<rgrd, rblk, 0, stream>>>(
                xpbuf, g_whh + (li + 1) * 4800, g_bhh + (li + 1) * 120);
        }
        // lay8 head on h[:, -1]
        final_head<<<dim3((CB + 255) / 256), dim3(256), 0, stream>>>(
            xpbuf + (size_t)(T_STEPS - 1) * GATES, out + c,
            mlp_w1 + 3 * 1600, mlp_b1 + 3 * 40, w_last, b_last, CB);
    }
}

// Round 7
// 2206.430 us; speedup vs baseline: 2.2673x; 1.6275x over previous
//
#include <hip/hip_runtime.h>
#include <hip/hip_fp16.h>
#include <cstdint>
#include <cstddef>

#define T_STEPS 512
#define HID 40
#define GATES 120

typedef _Float16 half8 __attribute__((ext_vector_type(8)));
typedef float f32x4 __attribute__((ext_vector_type(4)));

// Single-wave-block "barrier": lanes lockstep; only LDS completion ordering needed.
__device__ __forceinline__ void wavesync() { asm volatile("s_waitcnt lgkmcnt(0)" ::: "memory"); }
__device__ __forceinline__ float bperm(int srclane, float v) {
    return __int_as_float(__builtin_amdgcn_ds_bpermute(srclane << 2, __float_as_int(v)));
}
__device__ __forceinline__ float sigm(float x) { return 1.f / (1.f + __expf(-x)); }

// ---------------- weight prep (run once, tiny) ----------------
// out[NPAD][KPAD] f16: w[n][k] for n<N,k<K; bias b[n] at k==KPAD-1; else 0.
// (bias becomes a weight column; the A-side supplies 1.0 at that k.)
__global__ __launch_bounds__(256) void prep_pad(
    const float* __restrict__ w, const float* __restrict__ b,
    __half* __restrict__ out, int N, int K, int KPAD)
{
    const int idx = blockIdx.x * 256 + threadIdx.x;
    const int n = idx / KPAD, k = idx - n * KPAD;
    float v = 0.f;
    if (n < N) {
        if (k < K) v = w[n * K + k];
        else if (k == KPAD - 1) v = b[n];
    }
    out[idx] = __float2half(v);
}

// effpad[li][128][64] f16: wih_eff[n][k] = sum_j g_wih[li+1][n][j]*w2[li][j][k];
// k==63 column = bih_eff[n] = g_bih[li+1][n] + sum_j g_wih[li+1][n][j]*b2[li][j].
__global__ __launch_bounds__(256) void prep_eff(
    const float* __restrict__ g_wih, const float* __restrict__ g_bih,
    const float* __restrict__ w2, const float* __restrict__ b2,
    __half* __restrict__ out)
{
    const int li  = blockIdx.y;
    const int idx = blockIdx.x * 256 + threadIdx.x;   // over 128*64
    const int n = idx >> 6, k = idx & 63;
    float v = 0.f;
    if (n < GATES) {
        const float* wrow = g_wih + ((size_t)(li + 1) * GATES + n) * HID;
        if (k < HID) {
            for (int j = 0; j < HID; ++j) v += wrow[j] * w2[((size_t)li * HID + j) * HID + k];
        } else if (k == 63) {
            v = g_bih[(size_t)(li + 1) * GATES + n];
            for (int j = 0; j < HID; ++j) v += wrow[j] * b2[(size_t)li * HID + j];
        }
    }
    out[(size_t)li * 128 * 64 + idx] = __float2half(v);
}

// ---------------- MFMA gate precompute ----------------
// MODE 0: in = fp32 x [rows][20], single GEMM K=20(pad32), bias slot k=31.
// MODE 1: in = f16 rows (h at [0:40] of stride-120 rows), K=40(pad64), bias k=63.
// MODE 2: MLP GEMM1 (w1pad[48][64]) + leaky -> swizzled LDS -> GEMM2 (K=40 pad64).
// One wave = 16 rows per iteration. C/D layout (verified): n=lane&15, m=(lane>>4)*4+reg.
// A/B layout (16x16x32 f16): row/col = lane&15, k = (lane>>4)*8 + j (contiguous 8).
template<int MODE>
__global__ __launch_bounds__(256) void precomp_mfma(
    const void* in_, _Float16* xp,
    const _Float16* __restrict__ wihpad,  // [128][KP]
    const _Float16* __restrict__ w1pad,   // [48][64] (MODE 2 only)
    int nrows)
{
    __shared__ _Float16 s_v[4][1024];     // per-wave 2KB swizzled V tile [16][64]
    const int tid  = threadIdx.x;
    const int wid  = tid >> 6, lane = tid & 63;
    const int g    = lane >> 4, r = lane & 15;

    constexpr int KP  = (MODE == 0) ? 32 : 64;
    constexpr int NKS = KP / 32;

    // resident B fragments (gate weights): 8 n-tiles x NKS k-steps
    half8 bw[8][NKS];
    #pragma unroll
    for (int t = 0; t < 8; ++t)
        #pragma unroll
        for (int ks = 0; ks < NKS; ++ks)
            bw[t][ks] = *reinterpret_cast<const half8*>(wihpad + (t * 16 + r) * KP + ks * 32 + g * 8);

    half8 b1f[3][2];
    char* myv = nullptr;
    if constexpr (MODE == 2) {
        #pragma unroll
        for (int t = 0; t < 3; ++t)
            #pragma unroll
            for (int ks = 0; ks < 2; ++ks)
                b1f[t][ks] = *reinterpret_cast<const half8*>(w1pad + (t * 16 + r) * 64 + ks * 32 + g * 8);
        myv = (char*)&s_v[wid][0];
        // zero my 2KB region; plant 1.0 at k=63 of each row (bias slot for GEMM2)
        uint4 z; z.x = z.y = z.z = z.w = 0u;
        *reinterpret_cast<uint4*>(myv + lane * 32)      = z;
        *reinterpret_cast<uint4*>(myv + lane * 32 + 16) = z;
        wavesync();
        if (lane < 16)
            *reinterpret_cast<_Float16*>(myv + lane * 128 + (126 ^ ((lane & 7) << 4))) = (_Float16)1.f;
        wavesync();
    }

    const int w0     = blockIdx.x * 4 + wid;
    const int stride = gridDim.x * 64;    // rows per sweep (8 sweeps total)

    for (int rb = w0 * 16; rb < nrows; rb += stride) {
        // ---- A fragments ----
        half8 a0, a1;
        if constexpr (MODE == 0) {
            const float* xr = (const float*)in_ + (size_t)(rb + r) * 20;
            if (g < 2) {
                const float4 v0 = *reinterpret_cast<const float4*>(xr + g * 8);
                const float4 v1 = *reinterpret_cast<const float4*>(xr + g * 8 + 4);
                a0[0]=(_Float16)v0.x; a0[1]=(_Float16)v0.y; a0[2]=(_Float16)v0.z; a0[3]=(_Float16)v0.w;
                a0[4]=(_Float16)v1.x; a0[5]=(_Float16)v1.y; a0[6]=(_Float16)v1.z; a0[7]=(_Float16)v1.w;
            } else if (g == 2) {
                const float4 v0 = *reinterpret_cast<const float4*>(xr + 16);
                a0[0]=(_Float16)v0.x; a0[1]=(_Float16)v0.y; a0[2]=(_Float16)v0.z; a0[3]=(_Float16)v0.w;
                a0[4]=(_Float16)0.f; a0[5]=(_Float16)0.f; a0[6]=(_Float16)0.f; a0[7]=(_Float16)0.f;
            } else {
                #pragma unroll
                for (int j = 0; j < 8; ++j) a0[j] = (_Float16)0.f;
                a0[7] = (_Float16)1.f;    // bias slot k=31
            }
        } else {
            const _Float16* hr = (const _Float16*)in_ + (size_t)(rb + r) * GATES;
            a0 = *reinterpret_cast<const half8*>(hr + g * 8);          // k 0..31
            if (g == 0) {
                a1 = *reinterpret_cast<const half8*>(hr + 32);         // k 32..39
            } else {
                #pragma unroll
                for (int j = 0; j < 8; ++j) a1[j] = (_Float16)0.f;
                if (g == 3) a1[7] = (_Float16)1.f;                     // bias slot k=63
            }
        }

        if constexpr (MODE == 2) {
            // GEMM1: V = leaky(h@w1^T + b1) -> swizzled LDS [16][64] f16
            #pragma unroll
            for (int t = 0; t < 3; ++t) {
                f32x4 acc = {0.f, 0.f, 0.f, 0.f};
                acc = __builtin_amdgcn_mfma_f32_16x16x32_f16(a0, b1f[t][0], acc, 0, 0, 0);
                acc = __builtin_amdgcn_mfma_f32_16x16x32_f16(a1, b1f[t][1], acc, 0, 0, 0);
                const int n2 = (t * 16 + r) * 2;                       // byte col
                #pragma unroll
                for (int reg = 0; reg < 4; ++reg) {
                    const int m = g * 4 + reg;
                    float v = acc[reg];
                    v = v > 0.f ? v : 0.01f * v;
                    *reinterpret_cast<_Float16*>(myv + m * 128 + (n2 ^ ((m & 7) << 4))) = (_Float16)v;
                }
            }
            wavesync();
            const int sw = (r & 7) << 4;
            a0 = *reinterpret_cast<const half8*>(myv + r * 128 + ((g * 16) ^ sw));
            a1 = *reinterpret_cast<const half8*>(myv + r * 128 + ((64 + g * 16) ^ sw));
        }

        // GEMM2 (or the only GEMM): xp[row][gate] = pre-activations (bias baked in)
        #pragma unroll
        for (int t = 0; t < 8; ++t) {
            f32x4 acc = {0.f, 0.f, 0.f, 0.f};
            acc = __builtin_amdgcn_mfma_f32_16x16x32_f16(a0, bw[t][0], acc, 0, 0, 0);
            if constexpr (NKS == 2)
                acc = __builtin_amdgcn_mfma_f32_16x16x32_f16(a1, bw[t][1], acc, 0, 0, 0);
            const int n = t * 16 + r;
            if (n < GATES) {
                #pragma unroll
                for (int reg = 0; reg < 4; ++reg) {
                    const int m = g * 4 + reg;
                    xp[(size_t)(rb + m) * GATES + n] = (_Float16)acc[reg];
                }
            }
        }
    }
}

// ---------------- recurrence (unchanged from R6) ----------------
__global__ __launch_bounds__(64) void gru_rec(
    __half* xp,                      // [CB, T, 120], h written into [t][0:40]
    const float* __restrict__ whh,   // [120, 40]
    const float* __restrict__ bhh)   // [120]
{
    __shared__ float s_h[64];

    const int lane = threadIdx.x;
    const int e    = blockIdx.x;

    const int gA = lane;
    const int gB = (lane < 40) ? (80 + lane) : ((lane < 56) ? (24 + lane) : lane);

    float whA[HID], whB[HID];
    {
        const float4* hv = reinterpret_cast<const float4*>(whh);
        #pragma unroll
        for (int k = 0; k < HID / 4; ++k) {
            reinterpret_cast<float4*>(whA)[k] = hv[gA * (HID / 4) + k];
            reinterpret_cast<float4*>(whB)[k] = hv[gB * (HID / 4) + k];
        }
    }
    const float bhA = bhh[gA], bhB = bhh[gB];

    __half* xpb = xp + (size_t)e * T_STEPS * GATES;

    float hreg = 0.f;
    s_h[lane] = 0.f;

    __half a0 = xpb[gA],         c0 = xpb[gB];
    __half a1 = xpb[GATES + gA], c1 = xpb[GATES + gB];
    wavesync();

    for (int t = 0; t < T_STEPS; ++t) {
        __half a2 = a0, c2 = c0;
        if (t + 2 < T_STEPS) {
            a2 = xpb[(size_t)(t + 2) * GATES + gA];
            c2 = xpb[(size_t)(t + 2) * GATES + gB];
        }

        float4 hA = {0,0,0,0}, hB = {0,0,0,0};
        #pragma unroll
        for (int k = 0; k < HID / 4; ++k) {
            const float4 v = reinterpret_cast<const float4*>(s_h)[k];
            hA.x += whA[4*k+0]*v.x; hA.y += whA[4*k+1]*v.y;
            hA.z += whA[4*k+2]*v.z; hA.w += whA[4*k+3]*v.w;
            hB.x += whB[4*k+0]*v.x; hB.y += whB[4*k+1]*v.y;
            hB.z += whB[4*k+2]*v.z; hB.w += whB[4*k+3]*v.w;
        }
        const float shA = bhA + ((hA.x + hA.z) + (hA.y + hA.w));
        const float shB = bhB + ((hB.x + hB.z) + (hB.y + hB.w));
        const float xA  = __half2float(a0);
        const float xB  = __half2float(c0);
        const float sumA = xA + shA;
        const float sumB = xB + shB;
        const float zA = bperm(40 + lane, sumA);
        const float zB = bperm(16 + lane, sumB);

        if (lane < HID) {
            const float rr  = sigm(sumA);
            const float z   = sigm((lane < 24) ? zA : zB);
            const float pre = xB + rr * shB;
            const float ex  = __expf(-2.f * pre);
            const float n   = (1.f - ex) / (1.f + ex);
            hreg = (1.f - z) * n + z * hreg;
            s_h[lane] = hreg;
            xpb[(size_t)t * GATES + lane] = __float2half(hreg);
        }
        a0 = a1; c0 = c1; a1 = a2; c1 = c2;
        wavesync();
    }
}

// ---------------- head (unchanged from R6) ----------------
__global__ __launch_bounds__(256) void final_head(
    const __half* __restrict__ hbase,  // xpbuf + (T-1)*GATES
    float* __restrict__ outp,          // [CB]
    const float* __restrict__ w1, const float* __restrict__ b1,
    const float* __restrict__ wl, const float* __restrict__ bl, int n)
{
    __shared__ float s_w1[HID][HID + 1];
    __shared__ float s_b1[HID];
    __shared__ float s_wl[HID];
    for (int i = threadIdx.x; i < HID * HID; i += 256) s_w1[i / HID][i % HID] = w1[i];
    if (threadIdx.x < HID) { s_b1[threadIdx.x] = b1[threadIdx.x]; s_wl[threadIdx.x] = wl[threadIdx.x]; }
    __syncthreads();
    const int e = blockIdx.x * 256 + threadIdx.x;
    if (e >= n) return;

    alignas(16) __half hx[HID];
    const uint4* hr = reinterpret_cast<const uint4*>(hbase + (size_t)e * T_STEPS * GATES);
    #pragma unroll
    for (int q = 0; q < HID / 8; ++q) reinterpret_cast<uint4*>(hx)[q] = hr[q];
    float h[HID];
    #pragma unroll
    for (int k = 0; k < HID; ++k) h[k] = __half2float(hx[k]);

    float acc = bl[0];
    #pragma unroll
    for (int u = 0; u < HID; ++u) {
        float a = s_b1[u];
        #pragma unroll
        for (int d = 0; d < HID; ++d) a += s_w1[u][d] * h[d];
        a = a > 0.f ? a : 0.01f * a;
        acc += a * s_wl[u];
    }
    outp[e] = 1.f / (1.f + __expf(-acc));
}

extern "C" void kernel_launch(void* const* d_in, const int* in_sizes, int n_in,
                              void* d_out, int out_size, void* d_ws, size_t ws_size,
                              hipStream_t stream)
{
    const float* x      = (const float*)d_in[0];
    const float* g0_wih = (const float*)d_in[1];
    const float* g0_whh = (const float*)d_in[2];
    const float* g0_bih = (const float*)d_in[3];
    const float* g0_bhh = (const float*)d_in[4];
    const float* g_wih  = (const float*)d_in[5];   // [4,120,40]
    const float* g_whh  = (const float*)d_in[6];   // [4,120,40]
    const float* g_bih  = (const float*)d_in[7];   // [4,120]
    const float* g_bhh  = (const float*)d_in[8];   // [4,120]
    const float* mlp_w1 = (const float*)d_in[9];   // [4,40,40]
    const float* mlp_b1 = (const float*)d_in[10];  // [4,40]
    const float* mlp_w2 = (const float*)d_in[11];  // [3,40,40]
    const float* mlp_b2 = (const float*)d_in[12];  // [3,40]
    const float* w_last = (const float*)d_in[13];  // [1,40]
    const float* b_last = (const float*)d_in[14];  // [1]

    const int B = in_sizes[0] / (T_STEPS * 20);
    float* out = (float*)d_out;

    // ws: [w1pad 3x(48*64)][effpad 3x(128*64)][g0pad 128*32][g1pad 128*64] halves, then xp
    __half* wsz    = (__half*)d_ws;
    __half* w1pad  = wsz;                       // 3*3072
    __half* effpad = wsz + 3 * 3072;            // 3*8192
    __half* g0pad  = wsz + 9216 + 3 * 8192;     // 4096
    __half* g1pad  = g0pad + 4096;              // 8192
    _Float16* xpbuf = (_Float16*)(wsz + 46080); // 92160 B of weights, 16B aligned
    const size_t ws_rem = ws_size - 46080 * sizeof(__half);

    for (int li = 0; li < 3; ++li)
        prep_pad<<<dim3(12), dim3(256), 0, stream>>>(
            mlp_w1 + li * 1600, mlp_b1 + li * 40, w1pad + li * 3072, 40, 40, 64);
    prep_pad<<<dim3(16), dim3(256), 0, stream>>>(g0_wih, g0_bih, g0pad, 120, 20, 32);
    prep_pad<<<dim3(32), dim3(256), 0, stream>>>(g_wih, g_bih, g1pad, 120, 40, 64);
    prep_eff<<<dim3(32, 3), dim3(256), 0, stream>>>(g_wih, g_bih, mlp_w2, mlp_b2, effpad);

    const size_t per_e = (size_t)T_STEPS * GATES * sizeof(__half);  // 240 B/row
    int CB = B;
    while ((size_t)CB * per_e > ws_rem && CB > 64) CB >>= 1;

    for (int c = 0; c < B; c += CB) {
        const int  nrows = CB * T_STEPS;
        const dim3 pgrd(nrows / 512), pblk(256);
        const dim3 rgrd(CB), rblk(64);
        const float* xc = x + (size_t)c * T_STEPS * 20;

        precomp_mfma<0><<<pgrd, pblk, 0, stream>>>(
            xc, xpbuf, (const _Float16*)g0pad, nullptr, nrows);
        gru_rec<<<rgrd, rblk, 0, stream>>>((__half*)xpbuf, g0_whh, g0_bhh);

        precomp_mfma<1><<<pgrd, pblk, 0, stream>>>(
            xpbuf, xpbuf, (const _Float16*)g1pad, nullptr, nrows);
        gru_rec<<<rgrd, rblk, 0, stream>>>((__half*)xpbuf, g_whh + 0 * 4800, g_bhh + 0 * 120);

        for (int li = 0; li < 3; ++li) {
            precomp_mfma<2><<<pgrd, pblk, 0, stream>>>(
                xpbuf, xpbuf, (const _Float16*)(effpad + li * 8192),
                (const _Float16*)(w1pad + li * 3072), nrows);
            gru_rec<<<rgrd, rblk, 0, stream>>>(
                (__half*)xpbuf, g_whh + (li + 1) * 4800, g_bhh + (li + 1) * 120);
        }

        final_head<<<dim3((CB + 255) / 256), dim3(256), 0, stream>>>(
            (const __half*)(xpbuf + (size_t)(T_STEPS - 1) * GATES), out + c,
            mlp_w1 + 3 * 1600, mlp_b1 + 3 * 40, w_last, b_last, CB);
    }
}